// Round 12
// baseline (206.897 us; speedup 1.0000x reference)
//
#include <hip/hip_runtime.h>
#include <math.h>

// Closed-form replacement for the reference (see derivation in earlier rounds):
//   out = clip(x + 16*strength/(512*sqrt(S)) * v, 0, 1)
//   v[y,x] = cos(t1) - p*sin(t1) + cos(t2) - p*sin(t2) on the 2pi/512 grid
//   S from Parseval (analytic plane norm).
//
// R1 -> R3: ROWS 32->8 (6144 blocks), hoisted 4-deep load MLP, NT stores. ~59us.
// R3 -> R4: hw v_sin/v_cos (revolutions), no LDS. NEUTRAL -> not VALU-bound.
// R4 -> R5: persistent 2048-block grid. REGRESSED (62.5us). Plateau 2.4-2.6 TB/s
//           across structural changes -> memory-path ceiling suspected, common
//           factor = nontemporal stores.
// R6-R11: infra failures (acquisition timeouts / container). Bundled diagnostic:
//   (a) copy_probe: pure d_out=x float4 copy, same shape, plain stores ->
//       measures the in-harness memory ceiling for this access pattern.
//   (b) main kernel: R4 with PLAIN stores (the pending A/B vs NT).
//       Probe runs first; main kernel overwrites d_out -> correctness intact.

namespace {

constexpr int H = 512, W = 512, B = 32, C = 3;
constexpr int ROWS = 8;    // rows of one plane handled per block
constexpr int TPB = 256;   // 128 float4-lanes cover a 512-wide row; 2 rows at a time

typedef float floatx4 __attribute__((ext_vector_type(4)));

// ---------- diagnostic probe: pure copy, identical shape ----------
__global__ __launch_bounds__(TPB) void copy_probe(
    const float* __restrict__ xin, float* __restrict__ out)
{
    const int pl   = blockIdx.y;
    const int row0 = blockIdx.x * ROWS;
    const int xg   = (threadIdx.x & 127) << 2;
    const int rsub = threadIdx.x >> 7;

    const uint32_t off0 = (uint32_t)pl * (uint32_t)(H * W)
                        + (uint32_t)(row0 + rsub) * (uint32_t)W + (uint32_t)xg;
    const floatx4 vi0 = *reinterpret_cast<const floatx4*>(xin + off0);
    const floatx4 vi1 = *reinterpret_cast<const floatx4*>(xin + off0 + 2u * W);
    const floatx4 vi2 = *reinterpret_cast<const floatx4*>(xin + off0 + 4u * W);
    const floatx4 vi3 = *reinterpret_cast<const floatx4*>(xin + off0 + 6u * W);
    *reinterpret_cast<floatx4*>(out + off0)          = vi0;
    *reinterpret_cast<floatx4*>(out + off0 + 2u * W) = vi1;
    *reinterpret_cast<floatx4*>(out + off0 + 4u * W) = vi2;
    *reinterpret_cast<floatx4*>(out + off0 + 6u * W) = vi3;
}

// ---------- main kernel: R4 structure, plain stores ----------
__global__ __launch_bounds__(TPB) void fourier_noise_kernel(
    const float* __restrict__ xin,
    const float* __restrict__ phases,
    const float* __restrict__ strengths,
    const int* __restrict__ idx_h,
    const int* __restrict__ idx_w,
    float* __restrict__ out)
{
    const int pl   = blockIdx.y;            // plane 0..95  (= b*C + c)
    const int row0 = blockIdx.x * ROWS;
    const int xg   = (threadIdx.x & 127) << 2;  // column group 0..508
    const int rsub = threadIdx.x >> 7;          // 0 or 1 (wave-uniform)

    // ---- issue all global loads first ----
    const uint32_t off0 = (uint32_t)pl * (uint32_t)(H * W)
                        + (uint32_t)(row0 + rsub) * (uint32_t)W + (uint32_t)xg;
    const uint32_t off1 = off0 + 2u * W;
    const uint32_t off2 = off0 + 4u * W;
    const uint32_t off3 = off0 + 6u * W;
    const floatx4 vi0 = *reinterpret_cast<const floatx4*>(xin + off0);
    const floatx4 vi1 = *reinterpret_cast<const floatx4*>(xin + off1);
    const floatx4 vi2 = *reinterpret_cast<const floatx4*>(xin + off2);
    const floatx4 vi3 = *reinterpret_cast<const floatx4*>(xin + off3);

    // ---- scalar params (wave-uniform) ----
    const int b = pl / C;
    const int c = pl % C;
    int d = (c - b) % 3; if (d < 0) d += 3;     // CRT inverse pairing
    const int i = b + B * ((2 * d) % 3);

    const int   h0 = idx_h[i];
    const int   w0 = idx_w[i];
    const float p  = phases[i];
    const float st = strengths[pl];

    const float halfE = 0.5f * (1.0f + p * p);
    const float s1 = (((h0 & 255) == 0) && ((w0 & 255) == 0)) ? 1.0f : halfE;
    const float s2 = ((h0 == 255 || h0 == 511) && (w0 == 255 || w0 == 511)) ? 1.0f : halfE;
    const float g  = (16.0f / 512.0f) * st * rsqrtf(s1 + s2);

    const int h0r = 511 - h0;
    const int w0r = 511 - w0;
    constexpr float INV = 1.0f / 512.0f;   // grid-index -> revolutions

    // ---- per-thread column trig: hw sin/cos on exact revolutions ----
    float cx1[4], sx1[4], cx2[4], sx2[4];
#pragma unroll
    for (int j = 0; j < 4; ++j) {
        const int xx = xg + j;
        const float a1 = (float)((w0  * xx) & 511) * INV;
        const float a2 = (float)((w0r * xx) & 511) * INV;
        sx1[j] = __builtin_amdgcn_sinf(a1);
        cx1[j] = __builtin_amdgcn_cosf(a1);
        sx2[j] = __builtin_amdgcn_sinf(a2);
        cx2[j] = __builtin_amdgcn_cosf(a2);
    }

    // ---- per-thread row coefficients (rows rsub, rsub+2, rsub+4, rsub+6) ----
    float A1[4], B1[4], A2[4], B2[4];
#pragma unroll
    for (int it = 0; it < 4; ++it) {
        const int y = row0 + rsub + 2 * it;
        const float a1 = (float)((h0  * y) & 511) * INV;
        const float a2 = (float)((h0r * y) & 511) * INV;
        const float sy1 = __builtin_amdgcn_sinf(a1);
        const float cy1 = __builtin_amdgcn_cosf(a1);
        const float sy2 = __builtin_amdgcn_sinf(a2);
        const float cy2 = __builtin_amdgcn_cosf(a2);
        A1[it] = fmaf(-p, sy1, cy1);  B1[it] = -fmaf(p, cy1, sy1);
        A2[it] = fmaf(-p, sy2, cy2);  B2[it] = -fmaf(p, cy2, sy2);
    }

#define DO_ROW(vi, off, it)                                                     \
    {                                                                           \
        floatx4 vo;                                                             \
        _Pragma("unroll")                                                       \
        for (int j = 0; j < 4; ++j) {                                           \
            float v = cx1[j] * A1[it] + sx1[j] * B1[it]                         \
                    + cx2[j] * A2[it] + sx2[j] * B2[it];                        \
            vo[j] = fminf(fmaxf(fmaf(g, v, vi[j]), 0.0f), 1.0f);                \
        }                                                                       \
        *reinterpret_cast<floatx4*>(out + off) = vo;  /* plain store */         \
    }

    DO_ROW(vi0, off0, 0)
    DO_ROW(vi1, off1, 1)
    DO_ROW(vi2, off2, 2)
    DO_ROW(vi3, off3, 3)
#undef DO_ROW
}

} // namespace

extern "C" void kernel_launch(void* const* d_in, const int* in_sizes, int n_in,
                              void* d_out, int out_size, void* d_ws, size_t ws_size,
                              hipStream_t stream) {
    const float* x         = (const float*)d_in[0];
    const float* phases    = (const float*)d_in[1];
    const float* strengths = (const float*)d_in[2];
    const int*   idx_h     = (const int*)d_in[3];
    const int*   idx_w     = (const int*)d_in[4];
    float*       out       = (float*)d_out;

    dim3 grid(H / ROWS, B * C);  // 64 row-tiles x 96 planes = 6144 blocks

    // diagnostic: pure-copy ceiling probe (output fully overwritten below)
    copy_probe<<<grid, dim3(TPB), 0, stream>>>(x, out);

    fourier_noise_kernel<<<grid, dim3(TPB), 0, stream>>>(
        x, phases, strengths, idx_h, idx_w, out);
}